// Round 7
// baseline (1234.270 us; speedup 1.0000x reference)
//
#include <hip/hip_runtime.h>
#include <math.h>

#define H 128

typedef unsigned short u16;
typedef unsigned int u32;
typedef __attribute__((ext_vector_type(4))) u32 u32x4;
typedef __attribute__((ext_vector_type(8))) __bf16 bf16x8;
typedef __attribute__((ext_vector_type(4))) float f32x4;
typedef __attribute__((ext_vector_type(16))) float f32x16;

union Frag { u32x4 u; bf16x8 b; };

__device__ __forceinline__ u16 bfr(float f) {            // f32 -> bf16 RNE
    union { float f; u32 i; } v; v.f = f;
    u32 r = v.i + 0x7fffu + ((v.i >> 16) & 1u);
    return (u16)(r >> 16);
}
__device__ __forceinline__ u32 pack2(float lo, float hi) {
    return (u32)bfr(lo) | ((u32)bfr(hi) << 16);
}
__device__ __forceinline__ float bflo(u32 w) {           // low bf16 -> f32
    union { u32 i; float f; } v; v.i = w << 16; return v.f;
}
__device__ __forceinline__ float bfhi(u32 w) {           // high bf16 -> f32
    union { u32 i; float f; } v; v.i = w & 0xffff0000u; return v.f;
}
__device__ __forceinline__ float silu(float v) {
    float e = __expf(-v);
    return v * __builtin_amdgcn_rcpf(1.0f + e);
}
__device__ __forceinline__ bf16x8 f8frag(float4 lo, float4 hi) {
    Frag f;
    f.u = (u32x4){pack2(lo.x, lo.y), pack2(lo.z, lo.w),
                  pack2(hi.x, hi.y), pack2(hi.z, hi.w)};
    return f.b;
}
__device__ __forceinline__ f32x16 mfma(bf16x8 a, bf16x8 b, f32x16 c) {
    return __builtin_amdgcn_mfma_f32_32x32x16_bf16(a, b, c, 0, 0, 0);
}
__device__ __forceinline__ f32x4 mfma16(bf16x8 a, bf16x8 b, f32x4 c) {
    return __builtin_amdgcn_mfma_f32_16x16x32_bf16(a, b, c, 0, 0, 0);
}
// VALU-pipe cross-lane add within 16-lane rows: v += row_ror(v, N)
#define DPP_RADD(v, ctrl) \
    (v) += __int_as_float(__builtin_amdgcn_update_dpp(0, __float_as_int(v), (ctrl), 0xf, 0xf, 1))

// ---------------------------------------------------------------------------
// ws frag region (u32 units):
//   mw1s @ 0      : 4ct x 17kb x 64lane x 4   (msg w1^T 32x32 frags; kb16 = dist+b1)
//   mw2s @ 17408  : 4ct x  9kb x 64lane x 4   (msg w2^T 32x32 frags; kb8 = b2)
//   uw1s @ 26624  : 4ct x 17kb x 64lane x 4   (upd w1^T 32x32 frags; kb16 = b1)
//   uw2s @ 44032  : 4ct x  9kb x 64lane x 4   (upd w2^T 32x32 frags; kb8 = b2)
//   m16s @ 53248  : 5kb x 8mt x 64lane x 4    (msg w2 16x16 A-frags; kb4 = b2 row)
// 32x32 A-frag (ct,kb,lane): W[k=kb*16+(lane>>5)*8+j][ct*32+(lane&31)]
// 16x16 A-frag (kb,mt,lane): W[k=kb*32+(lane>>4)*8+j][mt*16+(lane&15)]
// ---------------------------------------------------------------------------
__global__ void prep_kernel(const float* __restrict__ mw1, const float* __restrict__ mb1,
                            const float* __restrict__ mw2, const float* __restrict__ mb2,
                            const float* __restrict__ uw1, const float* __restrict__ ub1,
                            const float* __restrict__ uw2, const float* __restrict__ ub2,
                            u32* __restrict__ ws) {
    int t = blockIdx.x * blockDim.x + threadIdx.x;
    if (t >= 15872) return;
    if (t >= 13312) {
        // ---- 16x16 A-frags of msg w2 (+ b2 row at kb=4) ----
        int slot = t - 13312;                 // (kb*8 + mt)*64 + lane
        int lane = slot & 63, fb = slot >> 6;
        int kb = fb >> 3, mt = fb & 7;
        int m = mt * 16 + (lane & 15);
        int quad = lane >> 4;
        u32 out[4];
        #pragma unroll
        for (int p = 0; p < 4; ++p) {
            float v[2];
            #pragma unroll
            for (int h = 0; h < 2; ++h) {
                int k = kb * 32 + quad * 8 + p * 2 + h;
                float val = 0.0f;
                if (k < 128)       val = mw2[(size_t)k * H + m];
                else if (k == 128) val = mb2[m];
                v[h] = val;
            }
            out[p] = pack2(v[0], v[1]);
        }
        u32* dst = ws + 53248 + (size_t)slot * 4;
        dst[0] = out[0]; dst[1] = out[1]; dst[2] = out[2]; dst[3] = out[3];
        return;
    }
    const float *W, *s0, *s1;
    int nK, slot, base;
    if (t < 4352)       { W = mw1; s0 = mw1 + 256 * H; s1 = mb1; nK = 256; slot = t;         base = 0;     }
    else if (t < 6656)  { W = mw2; s0 = mb2; s1 = nullptr;       nK = 128; slot = t - 4352;  base = 17408; }
    else if (t < 11008) { W = uw1; s0 = ub1; s1 = nullptr;       nK = 256; slot = t - 6656;  base = 26624; }
    else                { W = uw2; s0 = ub2; s1 = nullptr;       nK = 128; slot = t - 11008; base = 44032; }
    int lane = slot & 63, fb = slot >> 6;
    int ct, kb;
    if (nK == 256) { ct = fb / 17; kb = fb % 17; }
    else           { ct = fb / 9;  kb = fb % 9;  }
    int m = ct * 32 + (lane & 31);
    int q = lane >> 5;
    u32 out[4];
    #pragma unroll
    for (int p = 0; p < 4; ++p) {
        float v[2];
        #pragma unroll
        for (int h = 0; h < 2; ++h) {
            int k = kb * 16 + q * 8 + p * 2 + h;
            float val = 0.0f;
            if (k < nK)            val = W[(size_t)k * H + m];
            else if (k == nK)      val = s0 ? s0[m] : 0.0f;
            else if (k == nK + 1)  val = s1 ? s1[m] : 0.0f;
            v[h] = val;
        }
        out[p] = pack2(v[0], v[1]);
    }
    u32* dst = ws + base + (size_t)slot * 4;
    dst[0] = out[0]; dst[1] = out[1]; dst[2] = out[2]; dst[3] = out[3];
}

// ---------------------------------------------------------------------------
// pq_gemm: out[n] = x[n] @ W1[kbBase*16 : +128] (+ bias row if withBias).
// packP: store rows as packed bf16 (64 u32/row); else fp32 (128 f32/row).
// ---------------------------------------------------------------------------
__global__ __launch_bounds__(256, 2) void pq_gemm(
    const float* __restrict__ x, const u32* __restrict__ mw1s,
    void* __restrict__ outp, int kbBase, int withBias, int packP, int N, int nIter)
{
    const int lane = threadIdx.x & 63;
    const int q = lane >> 5, el = lane & 31;
    const int gw  = blockIdx.x * 4 + (threadIdx.x >> 6);
    const int gws = gridDim.x * 4;

    for (int it = gw; it < nIter; it += gws) {
        const int n0 = it * 64;
        const int nA = n0 + el, nB = n0 + 32 + el;
        const int ncA = (nA < N) ? nA : (N - 1);
        const int ncB = (nB < N) ? nB : (N - 1);
        const float* xA = x + (size_t)ncA * H;
        const float* xB = x + (size_t)ncB * H;

        f32x16 acc[2][4];
        #pragma unroll
        for (int s = 0; s < 2; ++s)
            #pragma unroll
            for (int ct = 0; ct < 4; ++ct) acc[s][ct] = (f32x16)0.0f;

        #pragma unroll
        for (int kb = 0; kb < 8; ++kb) {
            const int f = kb * 16 + q * 8;
            bf16x8 bA = f8frag(*(const float4*)(xA + f), *(const float4*)(xA + f + 4));
            bf16x8 bB = f8frag(*(const float4*)(xB + f), *(const float4*)(xB + f + 4));
            #pragma unroll
            for (int ct = 0; ct < 4; ++ct) {
                Frag a; a.u = *(const u32x4*)&mw1s[((size_t)(ct * 17 + kbBase + kb) * 64 + lane) * 4];
                acc[0][ct] = mfma(a.b, bA, acc[0][ct]);
                acc[1][ct] = mfma(a.b, bB, acc[1][ct]);
            }
        }
        if (withBias) {   // pad kb16: k=256 -> 0 (skip dist row), k=257 -> 1.0 (b1)
            Frag bp; bp.u = (u32x4){0, 0, 0, 0};
            if (q == 0) bp.u.x = pack2(0.0f, 1.0f);
            #pragma unroll
            for (int ct = 0; ct < 4; ++ct) {
                Frag a; a.u = *(const u32x4*)&mw1s[((size_t)(ct * 17 + 16) * 64 + lane) * 4];
                acc[0][ct] = mfma(a.b, bp.b, acc[0][ct]);
                acc[1][ct] = mfma(a.b, bp.b, acc[1][ct]);
            }
        }
        #pragma unroll
        for (int s = 0; s < 2; ++s) {
            const int nn = s ? nB : nA;
            if (nn < N) {
                if (packP) {
                    u32* prow = (u32*)outp + (size_t)nn * 64;
                    #pragma unroll
                    for (int ct = 0; ct < 4; ++ct)
                        #pragma unroll
                        for (int g = 0; g < 4; ++g) {
                            u32 a = pack2(acc[s][ct][4*g + 0], acc[s][ct][4*g + 1]);
                            u32 b = pack2(acc[s][ct][4*g + 2], acc[s][ct][4*g + 3]);
                            *(uint2*)(prow + ct * 16 + 4 * g + 2 * q) = make_uint2(a, b);
                        }
                } else {
                    float* orow = (float*)outp + (size_t)nn * H;
                    #pragma unroll
                    for (int ct = 0; ct < 4; ++ct)
                        #pragma unroll
                        for (int g = 0; g < 4; ++g) {
                            float4 v = { acc[s][ct][4*g + 0], acc[s][ct][4*g + 1],
                                         acc[s][ct][4*g + 2], acc[s][ct][4*g + 3] };
                            *(float4*)(orow + ct * 32 + 8 * g + 4 * q) = v;
                        }
                }
            }
        }
    }
}

// ---------------------------------------------------------------------------
// bucket_fill: per edge, slot = atomicAdd(deg[rec]); bucket[rec*64+slot] = (send, dist)
// ---------------------------------------------------------------------------
__global__ void bucket_fill(const float* __restrict__ pos, const int* __restrict__ ei,
                            int* __restrict__ deg, int2* __restrict__ bucket, int E)
{
    int e = blockIdx.x * blockDim.x + threadIdx.x;
    if (e >= E) return;
    const int s = ei[e];
    const int r = ei[E + e];
    const float dx = pos[s*3]   - pos[r*3];
    const float dy = pos[s*3+1] - pos[r*3+1];
    const float dz = pos[s*3+2] - pos[r*3+2];
    const float dist = sqrtf(dx*dx + dy*dy + dz*dz);
    int slot = atomicAdd(&deg[r], 1);
    if (slot < 64) bucket[(size_t)r * 64 + slot] = make_int2(s, __float_as_int(dist));
}

// ---------------------------------------------------------------------------
// aggregate (16x16 scheme): one wave per node n. 16-edge tiles.
//   h_e = silu(Pbf[send_e] + Q[n] + dist_e * wd)     (elementwise, per lane-col)
//   D = w2^T(16x16 A-frags, LDS) @ h (B-frag)        (mfma 16x16x32, K=128+b2)
//   sum += silu(D) per tile (correct for any deg)    (VALU)
//   reduce over 16 col-lanes via DPP row_ror adds    (VALU — zero LDS ops)
// Invalid lanes clamp address to a valid slot but zero their B-frag -> col=0,
// silu(0)=0 -> no contribution.
// ---------------------------------------------------------------------------
__global__ __launch_bounds__(256, 3) void aggregate_kernel(
    const u32* __restrict__ Pbf, const float* __restrict__ Q,
    const float* __restrict__ wd, const u32* __restrict__ ws16,
    const int* __restrict__ deg, const int2* __restrict__ bucket,
    float* __restrict__ out, int N)
{
    __shared__ u32x4 af[2048];                        // 32 KiB: w2 16x16 A-frags kb<4
    for (int i = threadIdx.x; i < 2048; i += 256) af[i] = ((const u32x4*)ws16)[i];

    const int lane = threadIdx.x & 63;
    const int quad = lane >> 4, col = lane & 15;
    u32 w2b[8];                                       // b2-row A-frag word (quad0-only)
    #pragma unroll
    for (int mt = 0; mt < 8; ++mt) w2b[mt] = ws16[((size_t)(32 + mt) * 64 + lane) * 4];
    __syncthreads();

    const int gw  = blockIdx.x * 4 + (threadIdx.x >> 6);
    const int gws = gridDim.x * 4;

    for (int n = gw; n < N; n += gws) {
        int dn = deg[n]; dn = (dn > 64) ? 64 : dn;
        const int nt = (dn + 15) >> 4;
        const float* Qn = Q + (size_t)n * H;

        f32x4 sum[8];
        #pragma unroll
        for (int mt = 0; mt < 8; ++mt) sum[mt] = (f32x4){0.f, 0.f, 0.f, 0.f};

        for (int t = 0; t < nt; ++t) {
            const int eIdx = t * 16 + col;
            const bool valid = eIdx < dn;
            const int eC = valid ? eIdx : (dn - 1);
            const int2 rec = bucket[(size_t)n * 64 + eC];
            const u32x4* Prow = (const u32x4*)(Pbf + (size_t)rec.x * 64);
            const float dist = __int_as_float(rec.y);

            f32x4 acc[8];
            #pragma unroll
            for (int mt = 0; mt < 8; ++mt) acc[mt] = (f32x4){0.f, 0.f, 0.f, 0.f};

            #pragma unroll
            for (int kb = 0; kb < 4; ++kb) {
                const int f = kb * 32 + quad * 8;
                const u32x4 pc = Prow[kb * 4 + quad];
                const float4 q0 = *(const float4*)(Qn + f);
                const float4 q1 = *(const float4*)(Qn + f + 4);
                const float4 w0 = *(const float4*)(wd + f);
                const float4 w1 = *(const float4*)(wd + f + 4);
                const float v0 = silu(bflo(pc.x) + q0.x + dist * w0.x);
                const float v1 = silu(bfhi(pc.x) + q0.y + dist * w0.y);
                const float v2 = silu(bflo(pc.y) + q0.z + dist * w0.z);
                const float v3 = silu(bfhi(pc.y) + q0.w + dist * w0.w);
                const float v4 = silu(bflo(pc.z) + q1.x + dist * w1.x);
                const float v5 = silu(bfhi(pc.z) + q1.y + dist * w1.y);
                const float v6 = silu(bflo(pc.w) + q1.z + dist * w1.z);
                const float v7 = silu(bfhi(pc.w) + q1.w + dist * w1.w);
                Frag bf;
                bf.u = (u32x4){pack2(v0, v1), pack2(v2, v3), pack2(v4, v5), pack2(v6, v7)};
                if (!valid) bf.u = (u32x4){0, 0, 0, 0};
                #pragma unroll
                for (int mt = 0; mt < 8; ++mt) {
                    Frag a; a.u = af[(kb * 8 + mt) * 64 + lane];
                    acc[mt] = mfma16(a.b, bf.b, acc[mt]);
                }
            }
            {   // b2 row (k=128): A/B nonzero only in quad0 word0
                Frag bb; bb.u = (u32x4){0, 0, 0, 0};
                if (quad == 0 && valid) bb.u.x = 0x00003F80u;   // bf16 1.0
                #pragma unroll
                for (int mt = 0; mt < 8; ++mt) {
                    Frag a; a.u = (u32x4){w2b[mt], 0, 0, 0};
                    acc[mt] = mfma16(a.b, bb.b, acc[mt]);
                }
            }
            #pragma unroll
            for (int mt = 0; mt < 8; ++mt) {
                sum[mt][0] += silu(acc[mt][0]);
                sum[mt][1] += silu(acc[mt][1]);
                sum[mt][2] += silu(acc[mt][2]);
                sum[mt][3] += silu(acc[mt][3]);
            }
        }

        // reduce over the 16 column-lanes: DPP row rotations, pure VALU
        #pragma unroll
        for (int mt = 0; mt < 8; ++mt)
            #pragma unroll
            for (int r = 0; r < 4; ++r) {
                float v = sum[mt][r];
                DPP_RADD(v, 0x128);   // row_ror:8
                DPP_RADD(v, 0x124);   // row_ror:4
                DPP_RADD(v, 0x122);   // row_ror:2
                DPP_RADD(v, 0x121);   // row_ror:1
                sum[mt][r] = v;
            }
        if (col == 0) {               // lanes 0,16,32,48: rows quad*4..+3 per mt
            float* orow = out + (size_t)n * H;
            #pragma unroll
            for (int mt = 0; mt < 8; ++mt) {
                float4 v = { sum[mt][0], sum[mt][1], sum[mt][2], sum[mt][3] };
                *(float4*)(orow + mt * 16 + quad * 4) = v;
            }
        }
    }
}

// ---------------------------------------------------------------------------
// FALLBACK (ws too small): round-3 edge kernel with fp32 atomics.
// ---------------------------------------------------------------------------
__global__ __launch_bounds__(256, 2) void edge_mfma(
    const float* __restrict__ x, const float* __restrict__ pos,
    const int* __restrict__ ei, const u32* __restrict__ ws,
    float* __restrict__ aggr, int E, int nIter)
{
    __shared__ u32 lds[16384];
    {
        const u32x4* src = (const u32x4*)ws;
        u32x4* dst = (u32x4*)lds;
        for (int i = threadIdx.x; i < 4096; i += 256) {
            int ln = i & 63, fb = i >> 6, ct = fb >> 4, kb = fb & 15;
            dst[i] = src[(ct * 17 + kb) * 64 + ln];
        }
    }
    __syncthreads();
    const u32* wsl1 = ws;
    const u32* wsl2 = ws + 17408;

    const int lane = threadIdx.x & 63;
    const int q = lane >> 5, el = lane & 31;
    const int gw  = blockIdx.x * 4 + (threadIdx.x >> 6);
    const int gws = gridDim.x * 4;

    for (int it = gw; it < nIter; it += gws) {
        const int e0 = it * 64;
        const int sA = ei[e0 + el],      rA = ei[E + e0 + el];
        const int sB = ei[e0 + 32 + el], rB = ei[E + e0 + 32 + el];
        float dA, dB;
        {
            float ax = pos[sA*3] - pos[rA*3], ay = pos[sA*3+1] - pos[rA*3+1], az = pos[sA*3+2] - pos[rA*3+2];
            dA = sqrtf(ax*ax + ay*ay + az*az);
            float bx = pos[sB*3] - pos[rB*3], by = pos[sB*3+1] - pos[rB*3+1], bz = pos[sB*3+2] - pos[rB*3+2];
            dB = sqrtf(bx*bx + by*by + bz*bz);
        }
        const float* xsA = x + (size_t)sA * H; const float* xrA = x + (size_t)rA * H;
        const float* xsB = x + (size_t)sB * H; const float* xrB = x + (size_t)rB * H;

        f32x16 acc[2][4];
        #pragma unroll
        for (int s = 0; s < 2; ++s)
            #pragma unroll
            for (int ct = 0; ct < 4; ++ct) acc[s][ct] = (f32x16)0.0f;

        #pragma unroll
        for (int kb = 0; kb < 16; ++kb) {
            const int f = kb * 16 + q * 8;
            const float* pA = (f < H) ? (xsA + f) : (xrA + f - H);
            const float* pB = (f < H) ? (xsB + f) : (xrB + f - H);
            bf16x8 bA = f8frag(*(const float4*)pA, *(const float4*)(pA + 4));
            bf16x8 bB = f8frag(*(const float4*)pB, *(const float4*)(pB + 4));
            #pragma unroll
            for (int ct = 0; ct < 4; ++ct) {
                Frag a; a.u = *(const u32x4*)&lds[((ct * 16 + kb) * 64 + lane) * 4];
                acc[0][ct] = mfma(a.b, bA, acc[0][ct]);
                acc[1][ct] = mfma(a.b, bB, acc[1][ct]);
            }
        }
        {
            Frag bA, bB;
            bA.u = (u32x4){0,0,0,0}; bB.u = (u32x4){0,0,0,0};
            if (q == 0) { bA.u.x = pack2(dA, 1.0f); bB.u.x = pack2(dB, 1.0f); }
            #pragma unroll
            for (int ct = 0; ct < 4; ++ct) {
                Frag a; a.u = *(const u32x4*)&wsl1[((size_t)(ct * 17 + 16) * 64 + lane) * 4];
                acc[0][ct] = mfma(a.b, bA.b, acc[0][ct]);
                acc[1][ct] = mfma(a.b, bB.b, acc[1][ct]);
            }
        }

        #pragma unroll
        for (int s = 0; s < 2; ++s) {
            const int ridx = s ? rB : rA;
            u32 hp[4][4][2];
            #pragma unroll
            for (int ct = 0; ct < 4; ++ct)
                #pragma unroll
                for (int g = 0; g < 4; ++g) {
                    float v0 = silu(acc[s][ct][4*g + 0]);
                    float v1 = silu(acc[s][ct][4*g + 1]);
                    float v2 = silu(acc[s][ct][4*g + 2]);
                    float v3 = silu(acc[s][ct][4*g + 3]);
                    hp[ct][g][0] = pack2(v0, v1);
                    hp[ct][g][1] = pack2(v2, v3);
                }

            f32x16 acc2[4];
            #pragma unroll
            for (int ct = 0; ct < 4; ++ct) acc2[ct] = (f32x16)0.0f;

            #pragma unroll
            for (int kb2 = 0; kb2 < 8; ++kb2) {
                const int om = 2 * kb2 + q;
                const int op = 2 * kb2 + 1 - q;
                u32 sv0 = hp[op >> 2][op & 3][0];
                u32 sv1 = hp[op >> 2][op & 3][1];
                u32 r0 = (u32)__shfl((int)sv0, lane ^ 32);
                u32 r1 = (u32)__shfl((int)sv1, lane ^ 32);
                u32 w0 = hp[om >> 2][om & 3][0];
                u32 w1v = hp[om >> 2][om & 3][1];
                Frag bf;
                if (q == 0) bf.u = (u32x4){w0, w1v, r0, r1};
                else        bf.u = (u32x4){r0, r1, w0, w1v};
                #pragma unroll
                for (int ct2 = 0; ct2 < 4; ++ct2) {
                    Frag a; a.u = *(const u32x4*)&wsl2[((size_t)(ct2 * 9 + kb2) * 64 + lane) * 4];
                    acc2[ct2] = mfma(a.b, bf.b, acc2[ct2]);
                }
            }
            {
                Frag bf; bf.u = (u32x4){0,0,0,0};
                if (q == 0) bf.u.x = 0x00003F80u;
                #pragma unroll
                for (int ct2 = 0; ct2 < 4; ++ct2) {
                    Frag a; a.u = *(const u32x4*)&wsl2[((size_t)(ct2 * 9 + 8) * 64 + lane) * 4];
                    acc2[ct2] = mfma(a.b, bf.b, acc2[ct2]);
                }
            }
            float* arow = aggr + (size_t)ridx * H;
            #pragma unroll
            for (int ct2 = 0; ct2 < 4; ++ct2)
                #pragma unroll
                for (int r = 0; r < 16; ++r) {
                    int m = ct2 * 32 + (r & 3) + 8 * (r >> 2) + 4 * q;
                    atomicAdd(arow + m, silu(acc2[ct2][r]));
                }
        }
    }
}

// ---------------------------------------------------------------------------
// Node update MLP: update = silu([x, aggr] @ uw1 + ub1) @ uw2 + ub2
// buf == d_out: aggr rows on entry, overwritten with the final update.
// ---------------------------------------------------------------------------
__global__ __launch_bounds__(256, 2) void node_mfma(
    const float* __restrict__ x, float* __restrict__ buf,
    const u32* __restrict__ ws, int N, int nIter)
{
    __shared__ u32 lds[16384];
    const u32* wsl1 = ws + 26624;
    const u32* wsl2 = ws + 44032;
    {
        const u32x4* src = (const u32x4*)wsl1;
        u32x4* dst = (u32x4*)lds;
        for (int i = threadIdx.x; i < 4096; i += 256) {
            int ln = i & 63, fb = i >> 6, ct = fb >> 4, kb = fb & 15;
            dst[i] = src[(ct * 17 + kb) * 64 + ln];
        }
    }
    __syncthreads();

    const int lane = threadIdx.x & 63;
    const int q = lane >> 5, el = lane & 31;
    const int gw  = blockIdx.x * 4 + (threadIdx.x >> 6);
    const int gws = gridDim.x * 4;

    for (int it = gw; it < nIter; it += gws) {
        const int n0 = it * 64;
        const int nA = n0 + el, nB = n0 + 32 + el;
        const int ncA = (nA < N) ? nA : (N - 1);
        const int ncB = (nB < N) ? nB : (N - 1);
        const float* xA = x + (size_t)ncA * H;  const float* gA = buf + (size_t)ncA * H;
        const float* xB = x + (size_t)ncB * H;  const float* gB = buf + (size_t)ncB * H;

        f32x16 acc[2][4];
        #pragma unroll
        for (int s = 0; s < 2; ++s)
            #pragma unroll
            for (int ct = 0; ct < 4; ++ct) acc[s][ct] = (f32x16)0.0f;

        #pragma unroll
        for (int kb = 0; kb < 16; ++kb) {
            const int f = kb * 16 + q * 8;
            const float* pA = (f < H) ? (xA + f) : (gA + f - H);
            const float* pB = (f < H) ? (xB + f) : (gB + f - H);
            bf16x8 bA = f8frag(*(const float4*)pA, *(const float4*)(pA + 4));
            bf16x8 bB = f8frag(*(const float4*)pB, *(const float4*)(pB + 4));
            #pragma unroll
            for (int ct = 0; ct < 4; ++ct) {
                Frag a; a.u = *(const u32x4*)&lds[((ct * 16 + kb) * 64 + lane) * 4];
                acc[0][ct] = mfma(a.b, bA, acc[0][ct]);
                acc[1][ct] = mfma(a.b, bB, acc[1][ct]);
            }
        }
        {
            Frag bp; bp.u = (u32x4){0,0,0,0};
            if (q == 0) bp.u.x = 0x00003F80u;
            #pragma unroll
            for (int ct = 0; ct < 4; ++ct) {
                Frag a; a.u = *(const u32x4*)&wsl1[((size_t)(ct * 17 + 16) * 64 + lane) * 4];
                acc[0][ct] = mfma(a.b, bp.b, acc[0][ct]);
                acc[1][ct] = mfma(a.b, bp.b, acc[1][ct]);
            }
        }

        #pragma unroll
        for (int s = 0; s < 2; ++s) {
            const int nn = s ? nB : nA;
            u32 hp[4][4][2];
            #pragma unroll
            for (int ct = 0; ct < 4; ++ct)
                #pragma unroll
                for (int g = 0; g < 4; ++g) {
                    float v0 = silu(acc[s][ct][4*g + 0]);
                    float v1 = silu(acc[s][ct][4*g + 1]);
                    float v2 = silu(acc[s][ct][4*g + 2]);
                    float v3 = silu(acc[s][ct][4*g + 3]);
                    hp[ct][g][0] = pack2(v0, v1);
                    hp[ct][g][1] = pack2(v2, v3);
                }

            f32x16 acc2[4];
            #pragma unroll
            for (int ct = 0; ct < 4; ++ct) acc2[ct] = (f32x16)0.0f;

            #pragma unroll
            for (int kb2 = 0; kb2 < 8; ++kb2) {
                const int om = 2 * kb2 + q;
                const int op = 2 * kb2 + 1 - q;
                u32 sv0 = hp[op >> 2][op & 3][0];
                u32 sv1 = hp[op >> 2][op & 3][1];
                u32 r0 = (u32)__shfl((int)sv0, lane ^ 32);
                u32 r1 = (u32)__shfl((int)sv1, lane ^ 32);
                u32 w0 = hp[om >> 2][om & 3][0];
                u32 w1v = hp[om >> 2][om & 3][1];
                Frag bf;
                if (q == 0) bf.u = (u32x4){w0, w1v, r0, r1};
                else        bf.u = (u32x4){r0, r1, w0, w1v};
                #pragma unroll
                for (int ct2 = 0; ct2 < 4; ++ct2) {
                    Frag a; a.u = *(const u32x4*)&wsl2[((size_t)(ct2 * 9 + kb2) * 64 + lane) * 4];
                    acc2[ct2] = mfma(a.b, bf.b, acc2[ct2]);
                }
            }
            {
                Frag bf; bf.u = (u32x4){0,0,0,0};
                if (q == 0) bf.u.x = 0x00003F80u;
                #pragma unroll
                for (int ct2 = 0; ct2 < 4; ++ct2) {
                    Frag a; a.u = *(const u32x4*)&wsl2[((size_t)(ct2 * 9 + 8) * 64 + lane) * 4];
                    acc2[ct2] = mfma(a.b, bf.b, acc2[ct2]);
                }
            }
            if (nn < N) {
                float* orow = buf + (size_t)nn * H;
                #pragma unroll
                for (int ct2 = 0; ct2 < 4; ++ct2)
                    #pragma unroll
                    for (int g = 0; g < 4; ++g) {
                        float4 v = { acc2[ct2][4*g + 0], acc2[ct2][4*g + 1],
                                     acc2[ct2][4*g + 2], acc2[ct2][4*g + 3] };
                        *(float4*)(orow + ct2 * 32 + 8 * g + 4 * q) = v;
                    }
            }
        }
    }
}

extern "C" void kernel_launch(void* const* d_in, const int* in_sizes, int n_in,
                              void* d_out, int out_size, void* d_ws, size_t ws_size,
                              hipStream_t stream) {
    const float* x    = (const float*)d_in[0];
    const float* pos  = (const float*)d_in[1];
    const int*   ei   = (const int*)d_in[2];
    const float* mw1  = (const float*)d_in[3];
    const float* mb1  = (const float*)d_in[4];
    const float* mw2  = (const float*)d_in[5];
    const float* mb2  = (const float*)d_in[6];
    const float* uw1  = (const float*)d_in[7];
    const float* ub1  = (const float*)d_in[8];
    const float* uw2  = (const float*)d_in[9];
    const float* ub2  = (const float*)d_in[10];

    const int N = in_sizes[0] / H;
    const int E = in_sizes[2] / 2;

    // ws layout (u32 units)
    const size_t FRAGS = 53248 + 10240;          // 32x32 frags + 16x16 msg-w2 frags
    const size_t PO = FRAGS;                     // P: N*64 u32 (packed bf16 rows)
    const size_t QO = PO + (size_t)N * 64;       // Q: N*H fp32
    const size_t DG = QO + (size_t)N * H;        // deg: N int
    const size_t BK = DG + (size_t)N;            // bucket: N*64 int2
    const size_t ENDu = BK + (size_t)N * 128;
    const size_t need_bytes = ENDu * 4;

    u32* ws = (u32*)d_ws;
    prep_kernel<<<62, 256, 0, stream>>>(mw1, mb1, mw2, mb2, uw1, ub1, uw2, ub2, ws);

    float* buf = (float*)d_out;
    const int nIterN = (N + 63) / 64;

    if (ws_size >= need_bytes) {
        // ---- gather path: no fp32 atomics ----
        u32*   Pb   = ws + PO;
        float* Qb   = (float*)(ws + QO);
        int*   deg  = (int*)(ws + DG);
        int2*  bkt  = (int2*)(ws + BK);

        pq_gemm<<<196, 256, 0, stream>>>(x, ws, Pb, 0, 0, 1, N, nIterN);
        pq_gemm<<<196, 256, 0, stream>>>(x, ws, Qb, 8, 1, 0, N, nIterN);

        hipMemsetAsync(deg, 0, (size_t)N * sizeof(int), stream);
        bucket_fill<<<(E + 255) / 256, 256, 0, stream>>>(pos, ei, deg, bkt, E);

        aggregate_kernel<<<1024, 256, 0, stream>>>(Pb, Qb, mw1 + 256 * H, ws + 53248,
                                                   deg, bkt, buf, N);
        node_mfma<<<256, 256, 0, stream>>>(x, buf, ws, N, nIterN);
    } else {
        // ---- fallback: round-3 atomic scatter path ----
        hipMemsetAsync(buf, 0, (size_t)N * H * sizeof(float), stream);
        edge_mfma<<<512, 256, 0, stream>>>(x, pos, ei, ws, buf, E, E / 64);
        node_mfma<<<256, 256, 0, stream>>>(x, buf, ws, N, nIterN);
    }
}

// Round 8
// 855.336 us; speedup vs baseline: 1.4430x; 1.4430x over previous
//
#include <hip/hip_runtime.h>
#include <math.h>

#define H 128

typedef unsigned short u16;
typedef unsigned int u32;
typedef __attribute__((ext_vector_type(4))) u32 u32x4;
typedef __attribute__((ext_vector_type(8))) __bf16 bf16x8;
typedef __attribute__((ext_vector_type(4))) float f32x4;
typedef __attribute__((ext_vector_type(16))) float f32x16;

union Frag { u32x4 u; bf16x8 b; };

__device__ __forceinline__ u16 bfr(float f) {            // f32 -> bf16 RNE
    union { float f; u32 i; } v; v.f = f;
    u32 r = v.i + 0x7fffu + ((v.i >> 16) & 1u);
    return (u16)(r >> 16);
}
__device__ __forceinline__ u32 pack2(float lo, float hi) {
    return (u32)bfr(lo) | ((u32)bfr(hi) << 16);
}
__device__ __forceinline__ float bflo(u32 w) {           // low bf16 -> f32
    union { u32 i; float f; } v; v.i = w << 16; return v.f;
}
__device__ __forceinline__ float bfhi(u32 w) {           // high bf16 -> f32
    union { u32 i; float f; } v; v.i = w & 0xffff0000u; return v.f;
}
__device__ __forceinline__ float silu(float v) {
    float e = __expf(-v);
    return v * __builtin_amdgcn_rcpf(1.0f + e);
}
__device__ __forceinline__ bf16x8 f8frag(float4 lo, float4 hi) {
    Frag f;
    f.u = (u32x4){pack2(lo.x, lo.y), pack2(lo.z, lo.w),
                  pack2(hi.x, hi.y), pack2(hi.z, hi.w)};
    return f.b;
}
__device__ __forceinline__ f32x16 mfma(bf16x8 a, bf16x8 b, f32x16 c) {
    return __builtin_amdgcn_mfma_f32_32x32x16_bf16(a, b, c, 0, 0, 0);
}
__device__ __forceinline__ f32x4 mfma16(bf16x8 a, bf16x8 b, f32x4 c) {
    return __builtin_amdgcn_mfma_f32_16x16x32_bf16(a, b, c, 0, 0, 0);
}
// VALU-pipe cross-lane add within 16-lane rows: v += row_ror(v, N)
#define DPP_RADD(v, ctrl) \
    (v) += __int_as_float(__builtin_amdgcn_update_dpp(0, __float_as_int(v), (ctrl), 0xf, 0xf, 1))

// ---------------------------------------------------------------------------
// ws frag region (u32 units):
//   mw1s @ 0      : 4ct x 17kb x 64lane x 4   (msg w1^T 32x32 frags; kb16 = dist+b1)
//   mw2s @ 17408  : 4ct x  9kb x 64lane x 4   (msg w2^T 32x32 frags; kb8 = b2)
//   uw1s @ 26624  : 4ct x 17kb x 64lane x 4   (upd w1^T 32x32 frags; kb16 = b1)
//   uw2s @ 44032  : 4ct x  9kb x 64lane x 4   (upd w2^T 32x32 frags; kb8 = b2)
//   m16s @ 53248  : 5kb x 8mt x 64lane x 4    (msg w2 16x16 A-frags; kb4 = b2 row)
// 32x32 A-frag (ct,kb,lane): W[k=kb*16+(lane>>5)*8+j][ct*32+(lane&31)]
// 16x16 A-frag (kb,mt,lane): W[k=kb*32+(lane>>4)*8+j][mt*16+(lane&15)]
// ---------------------------------------------------------------------------
__global__ void prep_kernel(const float* __restrict__ mw1, const float* __restrict__ mb1,
                            const float* __restrict__ mw2, const float* __restrict__ mb2,
                            const float* __restrict__ uw1, const float* __restrict__ ub1,
                            const float* __restrict__ uw2, const float* __restrict__ ub2,
                            u32* __restrict__ ws) {
    int t = blockIdx.x * blockDim.x + threadIdx.x;
    if (t >= 15872) return;
    if (t >= 13312) {
        // ---- 16x16 A-frags of msg w2 (+ b2 row at kb=4) ----
        int slot = t - 13312;                 // (kb*8 + mt)*64 + lane
        int lane = slot & 63, fb = slot >> 6;
        int kb = fb >> 3, mt = fb & 7;
        int m = mt * 16 + (lane & 15);
        int quad = lane >> 4;
        u32 out[4];
        #pragma unroll
        for (int p = 0; p < 4; ++p) {
            float v[2];
            #pragma unroll
            for (int h = 0; h < 2; ++h) {
                int k = kb * 32 + quad * 8 + p * 2 + h;
                float val = 0.0f;
                if (k < 128)       val = mw2[(size_t)k * H + m];
                else if (k == 128) val = mb2[m];
                v[h] = val;
            }
            out[p] = pack2(v[0], v[1]);
        }
        u32* dst = ws + 53248 + (size_t)slot * 4;
        dst[0] = out[0]; dst[1] = out[1]; dst[2] = out[2]; dst[3] = out[3];
        return;
    }
    const float *W, *s0, *s1;
    int nK, slot, base;
    if (t < 4352)       { W = mw1; s0 = mw1 + 256 * H; s1 = mb1; nK = 256; slot = t;         base = 0;     }
    else if (t < 6656)  { W = mw2; s0 = mb2; s1 = nullptr;       nK = 128; slot = t - 4352;  base = 17408; }
    else if (t < 11008) { W = uw1; s0 = ub1; s1 = nullptr;       nK = 256; slot = t - 6656;  base = 26624; }
    else                { W = uw2; s0 = ub2; s1 = nullptr;       nK = 128; slot = t - 11008; base = 44032; }
    int lane = slot & 63, fb = slot >> 6;
    int ct, kb;
    if (nK == 256) { ct = fb / 17; kb = fb % 17; }
    else           { ct = fb / 9;  kb = fb % 9;  }
    int m = ct * 32 + (lane & 31);
    int q = lane >> 5;
    u32 out[4];
    #pragma unroll
    for (int p = 0; p < 4; ++p) {
        float v[2];
        #pragma unroll
        for (int h = 0; h < 2; ++h) {
            int k = kb * 16 + q * 8 + p * 2 + h;
            float val = 0.0f;
            if (k < nK)            val = W[(size_t)k * H + m];
            else if (k == nK)      val = s0 ? s0[m] : 0.0f;
            else if (k == nK + 1)  val = s1 ? s1[m] : 0.0f;
            v[h] = val;
        }
        out[p] = pack2(v[0], v[1]);
    }
    u32* dst = ws + base + (size_t)slot * 4;
    dst[0] = out[0]; dst[1] = out[1]; dst[2] = out[2]; dst[3] = out[3];
}

// ---------------------------------------------------------------------------
// pq_gemm: out[n] = x[n] @ W1[kbBase*16 : +128] (+ bias row if withBias).
// packP: store rows as packed bf16 (64 u32/row); else fp32 (128 f32/row).
// ---------------------------------------------------------------------------
__global__ __launch_bounds__(256, 2) void pq_gemm(
    const float* __restrict__ x, const u32* __restrict__ mw1s,
    void* __restrict__ outp, int kbBase, int withBias, int packP, int N, int nIter)
{
    const int lane = threadIdx.x & 63;
    const int q = lane >> 5, el = lane & 31;
    const int gw  = blockIdx.x * 4 + (threadIdx.x >> 6);
    const int gws = gridDim.x * 4;

    for (int it = gw; it < nIter; it += gws) {
        const int n0 = it * 64;
        const int nA = n0 + el, nB = n0 + 32 + el;
        const int ncA = (nA < N) ? nA : (N - 1);
        const int ncB = (nB < N) ? nB : (N - 1);
        const float* xA = x + (size_t)ncA * H;
        const float* xB = x + (size_t)ncB * H;

        f32x16 acc[2][4];
        #pragma unroll
        for (int s = 0; s < 2; ++s)
            #pragma unroll
            for (int ct = 0; ct < 4; ++ct) acc[s][ct] = (f32x16)0.0f;

        #pragma unroll
        for (int kb = 0; kb < 8; ++kb) {
            const int f = kb * 16 + q * 8;
            bf16x8 bA = f8frag(*(const float4*)(xA + f), *(const float4*)(xA + f + 4));
            bf16x8 bB = f8frag(*(const float4*)(xB + f), *(const float4*)(xB + f + 4));
            #pragma unroll
            for (int ct = 0; ct < 4; ++ct) {
                Frag a; a.u = *(const u32x4*)&mw1s[((size_t)(ct * 17 + kbBase + kb) * 64 + lane) * 4];
                acc[0][ct] = mfma(a.b, bA, acc[0][ct]);
                acc[1][ct] = mfma(a.b, bB, acc[1][ct]);
            }
        }
        if (withBias) {   // pad kb16: k=256 -> 0 (skip dist row), k=257 -> 1.0 (b1)
            Frag bp; bp.u = (u32x4){0, 0, 0, 0};
            if (q == 0) bp.u.x = pack2(0.0f, 1.0f);
            #pragma unroll
            for (int ct = 0; ct < 4; ++ct) {
                Frag a; a.u = *(const u32x4*)&mw1s[((size_t)(ct * 17 + 16) * 64 + lane) * 4];
                acc[0][ct] = mfma(a.b, bp.b, acc[0][ct]);
                acc[1][ct] = mfma(a.b, bp.b, acc[1][ct]);
            }
        }
        #pragma unroll
        for (int s = 0; s < 2; ++s) {
            const int nn = s ? nB : nA;
            if (nn < N) {
                if (packP) {
                    u32* prow = (u32*)outp + (size_t)nn * 64;
                    #pragma unroll
                    for (int ct = 0; ct < 4; ++ct)
                        #pragma unroll
                        for (int g = 0; g < 4; ++g) {
                            u32 a = pack2(acc[s][ct][4*g + 0], acc[s][ct][4*g + 1]);
                            u32 b = pack2(acc[s][ct][4*g + 2], acc[s][ct][4*g + 3]);
                            *(uint2*)(prow + ct * 16 + 4 * g + 2 * q) = make_uint2(a, b);
                        }
                } else {
                    float* orow = (float*)outp + (size_t)nn * H;
                    #pragma unroll
                    for (int ct = 0; ct < 4; ++ct)
                        #pragma unroll
                        for (int g = 0; g < 4; ++g) {
                            float4 v = { acc[s][ct][4*g + 0], acc[s][ct][4*g + 1],
                                         acc[s][ct][4*g + 2], acc[s][ct][4*g + 3] };
                            *(float4*)(orow + ct * 32 + 8 * g + 4 * q) = v;
                        }
                }
            }
        }
    }
}

// ---------------------------------------------------------------------------
// bucket_fill: per edge, slot = atomicAdd(deg[rec]); bucket[rec*64+slot] = (send, dist)
// ---------------------------------------------------------------------------
__global__ void bucket_fill(const float* __restrict__ pos, const int* __restrict__ ei,
                            int* __restrict__ deg, int2* __restrict__ bucket, int E)
{
    int e = blockIdx.x * blockDim.x + threadIdx.x;
    if (e >= E) return;
    const int s = ei[e];
    const int r = ei[E + e];
    const float dx = pos[s*3]   - pos[r*3];
    const float dy = pos[s*3+1] - pos[r*3+1];
    const float dz = pos[s*3+2] - pos[r*3+2];
    const float dist = sqrtf(dx*dx + dy*dy + dz*dz);
    int slot = atomicAdd(&deg[r], 1);
    if (slot < 64) bucket[(size_t)r * 64 + slot] = make_int2(s, __float_as_int(dist));
}

// ---------------------------------------------------------------------------
// aggregate (16x16 scheme): one wave per node n. 16-edge tiles.
//   h_e = silu(Pbf[send_e] + Q[n] + dist_e * wd)     (elementwise, per lane-col)
//   D = w2^T(16x16 A-frags, LDS) @ h (B-frag)        (mfma 16x16x32, K=128+b2)
//   sum += silu(D) per tile (correct for any deg)    (VALU)
//   reduce over 16 col-lanes via DPP row_ror adds    (VALU — zero LDS ops)
// Invalid lanes clamp address to a valid slot but zero their B-frag -> col=0,
// silu(0)=0 -> no contribution.
// __launch_bounds__(256,2) — 256-reg cap. DO NOT use (256,3): the 170-reg cap
// spills the sum/acc accumulators -> GB-scale scratch traffic (R5, R7 both
// measured ~2-5 GB WRITE, ~5x slowdown). (256,2) measured clean (R6: 83/25 MB).
// ---------------------------------------------------------------------------
__global__ __launch_bounds__(256, 2) void aggregate_kernel(
    const u32* __restrict__ Pbf, const float* __restrict__ Q,
    const float* __restrict__ wd, const u32* __restrict__ ws16,
    const int* __restrict__ deg, const int2* __restrict__ bucket,
    float* __restrict__ out, int N)
{
    __shared__ u32x4 af[2048];                        // 32 KiB: w2 16x16 A-frags kb<4
    for (int i = threadIdx.x; i < 2048; i += 256) af[i] = ((const u32x4*)ws16)[i];

    const int lane = threadIdx.x & 63;
    const int quad = lane >> 4, col = lane & 15;
    u32 w2b[8];                                       // b2-row A-frag word (quad0-only)
    #pragma unroll
    for (int mt = 0; mt < 8; ++mt) w2b[mt] = ws16[((size_t)(32 + mt) * 64 + lane) * 4];
    __syncthreads();

    const int gw  = blockIdx.x * 4 + (threadIdx.x >> 6);
    const int gws = gridDim.x * 4;

    for (int n = gw; n < N; n += gws) {
        int dn = deg[n]; dn = (dn > 64) ? 64 : dn;
        const int nt = (dn + 15) >> 4;
        const float* Qn = Q + (size_t)n * H;

        f32x4 sum[8];
        #pragma unroll
        for (int mt = 0; mt < 8; ++mt) sum[mt] = (f32x4){0.f, 0.f, 0.f, 0.f};

        for (int t = 0; t < nt; ++t) {
            const int eIdx = t * 16 + col;
            const bool valid = eIdx < dn;
            const int eC = valid ? eIdx : (dn - 1);
            const int2 rec = bucket[(size_t)n * 64 + eC];
            const u32x4* Prow = (const u32x4*)(Pbf + (size_t)rec.x * 64);
            const float dist = __int_as_float(rec.y);

            f32x4 acc[8];
            #pragma unroll
            for (int mt = 0; mt < 8; ++mt) acc[mt] = (f32x4){0.f, 0.f, 0.f, 0.f};

            #pragma unroll
            for (int kb = 0; kb < 4; ++kb) {
                const int f = kb * 32 + quad * 8;
                const u32x4 pc = Prow[kb * 4 + quad];
                const float4 q0 = *(const float4*)(Qn + f);
                const float4 q1 = *(const float4*)(Qn + f + 4);
                const float4 w0 = *(const float4*)(wd + f);
                const float4 w1 = *(const float4*)(wd + f + 4);
                const float v0 = silu(bflo(pc.x) + q0.x + dist * w0.x);
                const float v1 = silu(bfhi(pc.x) + q0.y + dist * w0.y);
                const float v2 = silu(bflo(pc.y) + q0.z + dist * w0.z);
                const float v3 = silu(bfhi(pc.y) + q0.w + dist * w0.w);
                const float v4 = silu(bflo(pc.z) + q1.x + dist * w1.x);
                const float v5 = silu(bfhi(pc.z) + q1.y + dist * w1.y);
                const float v6 = silu(bflo(pc.w) + q1.z + dist * w1.z);
                const float v7 = silu(bfhi(pc.w) + q1.w + dist * w1.w);
                Frag bf;
                bf.u = (u32x4){pack2(v0, v1), pack2(v2, v3), pack2(v4, v5), pack2(v6, v7)};
                if (!valid) bf.u = (u32x4){0, 0, 0, 0};
                #pragma unroll
                for (int mt = 0; mt < 8; ++mt) {
                    Frag a; a.u = af[(kb * 8 + mt) * 64 + lane];
                    acc[mt] = mfma16(a.b, bf.b, acc[mt]);
                }
            }
            {   // b2 row (k=128): A/B nonzero only in quad0 word0
                Frag bb; bb.u = (u32x4){0, 0, 0, 0};
                if (quad == 0 && valid) bb.u.x = 0x00003F80u;   // bf16 1.0
                #pragma unroll
                for (int mt = 0; mt < 8; ++mt) {
                    Frag a; a.u = (u32x4){w2b[mt], 0, 0, 0};
                    acc[mt] = mfma16(a.b, bb.b, acc[mt]);
                }
            }
            #pragma unroll
            for (int mt = 0; mt < 8; ++mt) {
                sum[mt][0] += silu(acc[mt][0]);
                sum[mt][1] += silu(acc[mt][1]);
                sum[mt][2] += silu(acc[mt][2]);
                sum[mt][3] += silu(acc[mt][3]);
            }
        }

        // reduce over the 16 column-lanes: DPP row rotations, pure VALU
        #pragma unroll
        for (int mt = 0; mt < 8; ++mt)
            #pragma unroll
            for (int r = 0; r < 4; ++r) {
                float v = sum[mt][r];
                DPP_RADD(v, 0x128);   // row_ror:8
                DPP_RADD(v, 0x124);   // row_ror:4
                DPP_RADD(v, 0x122);   // row_ror:2
                DPP_RADD(v, 0x121);   // row_ror:1
                sum[mt][r] = v;
            }
        if (col == 0) {               // lanes 0,16,32,48: rows quad*4..+3 per mt
            float* orow = out + (size_t)n * H;
            #pragma unroll
            for (int mt = 0; mt < 8; ++mt) {
                float4 v = { sum[mt][0], sum[mt][1], sum[mt][2], sum[mt][3] };
                *(float4*)(orow + mt * 16 + quad * 4) = v;
            }
        }
    }
}

// ---------------------------------------------------------------------------
// FALLBACK (ws too small): round-3 edge kernel with fp32 atomics.
// ---------------------------------------------------------------------------
__global__ __launch_bounds__(256, 2) void edge_mfma(
    const float* __restrict__ x, const float* __restrict__ pos,
    const int* __restrict__ ei, const u32* __restrict__ ws,
    float* __restrict__ aggr, int E, int nIter)
{
    __shared__ u32 lds[16384];
    {
        const u32x4* src = (const u32x4*)ws;
        u32x4* dst = (u32x4*)lds;
        for (int i = threadIdx.x; i < 4096; i += 256) {
            int ln = i & 63, fb = i >> 6, ct = fb >> 4, kb = fb & 15;
            dst[i] = src[(ct * 17 + kb) * 64 + ln];
        }
    }
    __syncthreads();
    const u32* wsl1 = ws;
    const u32* wsl2 = ws + 17408;

    const int lane = threadIdx.x & 63;
    const int q = lane >> 5, el = lane & 31;
    const int gw  = blockIdx.x * 4 + (threadIdx.x >> 6);
    const int gws = gridDim.x * 4;

    for (int it = gw; it < nIter; it += gws) {
        const int e0 = it * 64;
        const int sA = ei[e0 + el],      rA = ei[E + e0 + el];
        const int sB = ei[e0 + 32 + el], rB = ei[E + e0 + 32 + el];
        float dA, dB;
        {
            float ax = pos[sA*3] - pos[rA*3], ay = pos[sA*3+1] - pos[rA*3+1], az = pos[sA*3+2] - pos[rA*3+2];
            dA = sqrtf(ax*ax + ay*ay + az*az);
            float bx = pos[sB*3] - pos[rB*3], by = pos[sB*3+1] - pos[rB*3+1], bz = pos[sB*3+2] - pos[rB*3+2];
            dB = sqrtf(bx*bx + by*by + bz*bz);
        }
        const float* xsA = x + (size_t)sA * H; const float* xrA = x + (size_t)rA * H;
        const float* xsB = x + (size_t)sB * H; const float* xrB = x + (size_t)rB * H;

        f32x16 acc[2][4];
        #pragma unroll
        for (int s = 0; s < 2; ++s)
            #pragma unroll
            for (int ct = 0; ct < 4; ++ct) acc[s][ct] = (f32x16)0.0f;

        #pragma unroll
        for (int kb = 0; kb < 16; ++kb) {
            const int f = kb * 16 + q * 8;
            const float* pA = (f < H) ? (xsA + f) : (xrA + f - H);
            const float* pB = (f < H) ? (xsB + f) : (xrB + f - H);
            bf16x8 bA = f8frag(*(const float4*)pA, *(const float4*)(pA + 4));
            bf16x8 bB = f8frag(*(const float4*)pB, *(const float4*)(pB + 4));
            #pragma unroll
            for (int ct = 0; ct < 4; ++ct) {
                Frag a; a.u = *(const u32x4*)&lds[((ct * 16 + kb) * 64 + lane) * 4];
                acc[0][ct] = mfma(a.b, bA, acc[0][ct]);
                acc[1][ct] = mfma(a.b, bB, acc[1][ct]);
            }
        }
        {
            Frag bA, bB;
            bA.u = (u32x4){0,0,0,0}; bB.u = (u32x4){0,0,0,0};
            if (q == 0) { bA.u.x = pack2(dA, 1.0f); bB.u.x = pack2(dB, 1.0f); }
            #pragma unroll
            for (int ct = 0; ct < 4; ++ct) {
                Frag a; a.u = *(const u32x4*)&wsl1[((size_t)(ct * 17 + 16) * 64 + lane) * 4];
                acc[0][ct] = mfma(a.b, bA.b, acc[0][ct]);
                acc[1][ct] = mfma(a.b, bB.b, acc[1][ct]);
            }
        }

        #pragma unroll
        for (int s = 0; s < 2; ++s) {
            const int ridx = s ? rB : rA;
            u32 hp[4][4][2];
            #pragma unroll
            for (int ct = 0; ct < 4; ++ct)
                #pragma unroll
                for (int g = 0; g < 4; ++g) {
                    float v0 = silu(acc[s][ct][4*g + 0]);
                    float v1 = silu(acc[s][ct][4*g + 1]);
                    float v2 = silu(acc[s][ct][4*g + 2]);
                    float v3 = silu(acc[s][ct][4*g + 3]);
                    hp[ct][g][0] = pack2(v0, v1);
                    hp[ct][g][1] = pack2(v2, v3);
                }

            f32x16 acc2[4];
            #pragma unroll
            for (int ct = 0; ct < 4; ++ct) acc2[ct] = (f32x16)0.0f;

            #pragma unroll
            for (int kb2 = 0; kb2 < 8; ++kb2) {
                const int om = 2 * kb2 + q;
                const int op = 2 * kb2 + 1 - q;
                u32 sv0 = hp[op >> 2][op & 3][0];
                u32 sv1 = hp[op >> 2][op & 3][1];
                u32 r0 = (u32)__shfl((int)sv0, lane ^ 32);
                u32 r1 = (u32)__shfl((int)sv1, lane ^ 32);
                u32 w0 = hp[om >> 2][om & 3][0];
                u32 w1v = hp[om >> 2][om & 3][1];
                Frag bf;
                if (q == 0) bf.u = (u32x4){w0, w1v, r0, r1};
                else        bf.u = (u32x4){r0, r1, w0, w1v};
                #pragma unroll
                for (int ct2 = 0; ct2 < 4; ++ct2) {
                    Frag a; a.u = *(const u32x4*)&wsl2[((size_t)(ct2 * 9 + kb2) * 64 + lane) * 4];
                    acc2[ct2] = mfma(a.b, bf.b, acc2[ct2]);
                }
            }
            {
                Frag bf; bf.u = (u32x4){0,0,0,0};
                if (q == 0) bf.u.x = 0x00003F80u;
                #pragma unroll
                for (int ct2 = 0; ct2 < 4; ++ct2) {
                    Frag a; a.u = *(const u32x4*)&wsl2[((size_t)(ct2 * 9 + 8) * 64 + lane) * 4];
                    acc2[ct2] = mfma(a.b, bf.b, acc2[ct2]);
                }
            }
            float* arow = aggr + (size_t)ridx * H;
            #pragma unroll
            for (int ct2 = 0; ct2 < 4; ++ct2)
                #pragma unroll
                for (int r = 0; r < 16; ++r) {
                    int m = ct2 * 32 + (r & 3) + 8 * (r >> 2) + 4 * q;
                    atomicAdd(arow + m, silu(acc2[ct2][r]));
                }
        }
    }
}

// ---------------------------------------------------------------------------
// Node update MLP: update = silu([x, aggr] @ uw1 + ub1) @ uw2 + ub2
// buf == d_out: aggr rows on entry, overwritten with the final update.
// ---------------------------------------------------------------------------
__global__ __launch_bounds__(256, 2) void node_mfma(
    const float* __restrict__ x, float* __restrict__ buf,
    const u32* __restrict__ ws, int N, int nIter)
{
    __shared__ u32 lds[16384];
    const u32* wsl1 = ws + 26624;
    const u32* wsl2 = ws + 44032;
    {
        const u32x4* src = (const u32x4*)wsl1;
        u32x4* dst = (u32x4*)lds;
        for (int i = threadIdx.x; i < 4096; i += 256) {
            int ln = i & 63, fb = i >> 6, ct = fb >> 4, kb = fb & 15;
            dst[i] = src[(ct * 17 + kb) * 64 + ln];
        }
    }
    __syncthreads();

    const int lane = threadIdx.x & 63;
    const int q = lane >> 5, el = lane & 31;
    const int gw  = blockIdx.x * 4 + (threadIdx.x >> 6);
    const int gws = gridDim.x * 4;

    for (int it = gw; it < nIter; it += gws) {
        const int n0 = it * 64;
        const int nA = n0 + el, nB = n0 + 32 + el;
        const int ncA = (nA < N) ? nA : (N - 1);
        const int ncB = (nB < N) ? nB : (N - 1);
        const float* xA = x + (size_t)ncA * H;  const float* gA = buf + (size_t)ncA * H;
        const float* xB = x + (size_t)ncB * H;  const float* gB = buf + (size_t)ncB * H;

        f32x16 acc[2][4];
        #pragma unroll
        for (int s = 0; s < 2; ++s)
            #pragma unroll
            for (int ct = 0; ct < 4; ++ct) acc[s][ct] = (f32x16)0.0f;

        #pragma unroll
        for (int kb = 0; kb < 16; ++kb) {
            const int f = kb * 16 + q * 8;
            const float* pA = (f < H) ? (xA + f) : (gA + f - H);
            const float* pB = (f < H) ? (xB + f) : (gB + f - H);
            bf16x8 bA = f8frag(*(const float4*)pA, *(const float4*)(pA + 4));
            bf16x8 bB = f8frag(*(const float4*)pB, *(const float4*)(pB + 4));
            #pragma unroll
            for (int ct = 0; ct < 4; ++ct) {
                Frag a; a.u = *(const u32x4*)&lds[((ct * 16 + kb) * 64 + lane) * 4];
                acc[0][ct] = mfma(a.b, bA, acc[0][ct]);
                acc[1][ct] = mfma(a.b, bB, acc[1][ct]);
            }
        }
        {
            Frag bp; bp.u = (u32x4){0,0,0,0};
            if (q == 0) bp.u.x = 0x00003F80u;
            #pragma unroll
            for (int ct = 0; ct < 4; ++ct) {
                Frag a; a.u = *(const u32x4*)&wsl1[((size_t)(ct * 17 + 16) * 64 + lane) * 4];
                acc[0][ct] = mfma(a.b, bp.b, acc[0][ct]);
                acc[1][ct] = mfma(a.b, bp.b, acc[1][ct]);
            }
        }

        #pragma unroll
        for (int s = 0; s < 2; ++s) {
            const int nn = s ? nB : nA;
            u32 hp[4][4][2];
            #pragma unroll
            for (int ct = 0; ct < 4; ++ct)
                #pragma unroll
                for (int g = 0; g < 4; ++g) {
                    float v0 = silu(acc[s][ct][4*g + 0]);
                    float v1 = silu(acc[s][ct][4*g + 1]);
                    float v2 = silu(acc[s][ct][4*g + 2]);
                    float v3 = silu(acc[s][ct][4*g + 3]);
                    hp[ct][g][0] = pack2(v0, v1);
                    hp[ct][g][1] = pack2(v2, v3);
                }

            f32x16 acc2[4];
            #pragma unroll
            for (int ct = 0; ct < 4; ++ct) acc2[ct] = (f32x16)0.0f;

            #pragma unroll
            for (int kb2 = 0; kb2 < 8; ++kb2) {
                const int om = 2 * kb2 + q;
                const int op = 2 * kb2 + 1 - q;
                u32 sv0 = hp[op >> 2][op & 3][0];
                u32 sv1 = hp[op >> 2][op & 3][1];
                u32 r0 = (u32)__shfl((int)sv0, lane ^ 32);
                u32 r1 = (u32)__shfl((int)sv1, lane ^ 32);
                u32 w0 = hp[om >> 2][om & 3][0];
                u32 w1v = hp[om >> 2][om & 3][1];
                Frag bf;
                if (q == 0) bf.u = (u32x4){w0, w1v, r0, r1};
                else        bf.u = (u32x4){r0, r1, w0, w1v};
                #pragma unroll
                for (int ct2 = 0; ct2 < 4; ++ct2) {
                    Frag a; a.u = *(const u32x4*)&wsl2[((size_t)(ct2 * 9 + kb2) * 64 + lane) * 4];
                    acc2[ct2] = mfma(a.b, bf.b, acc2[ct2]);
                }
            }
            {
                Frag bf; bf.u = (u32x4){0,0,0,0};
                if (q == 0) bf.u.x = 0x00003F80u;
                #pragma unroll
                for (int ct2 = 0; ct2 < 4; ++ct2) {
                    Frag a; a.u = *(const u32x4*)&wsl2[((size_t)(ct2 * 9 + 8) * 64 + lane) * 4];
                    acc2[ct2] = mfma(a.b, bf.b, acc2[ct2]);
                }
            }
            if (nn < N) {
                float* orow = buf + (size_t)nn * H;
                #pragma unroll
                for (int ct2 = 0; ct2 < 4; ++ct2)
                    #pragma unroll
                    for (int g = 0; g < 4; ++g) {
                        float4 v = { acc2[ct2][4*g + 0], acc2[ct2][4*g + 1],
                                     acc2[ct2][4*g + 2], acc2[ct2][4*g + 3] };
                        *(float4*)(orow + ct2 * 32 + 8 * g + 4 * q) = v;
                    }
            }
        }
    }
}

extern "C" void kernel_launch(void* const* d_in, const int* in_sizes, int n_in,
                              void* d_out, int out_size, void* d_ws, size_t ws_size,
                              hipStream_t stream) {
    const float* x    = (const float*)d_in[0];
    const float* pos  = (const float*)d_in[1];
    const int*   ei   = (const int*)d_in[2];
    const float* mw1  = (const float*)d_in[3];
    const float* mb1  = (const float*)d_in[4];
    const float* mw2  = (const float*)d_in[5];
    const float* mb2  = (const float*)d_in[6];
    const float* uw1  = (const float*)d_in[7];
    const float* ub1  = (const float*)d_in[8];
    const float* uw2  = (const float*)d_in[9];
    const float* ub2  = (const float*)d_in[10];

    const int N = in_sizes[0] / H;
    const int E = in_sizes[2] / 2;

    // ws layout (u32 units)
    const size_t FRAGS = 53248 + 10240;          // 32x32 frags + 16x16 msg-w2 frags
    const size_t PO = FRAGS;                     // P: N*64 u32 (packed bf16 rows)
    const size_t QO = PO + (size_t)N * 64;       // Q: N*H fp32
    const size_t DG = QO + (size_t)N * H;        // deg: N int
    const size_t BK = DG + (size_t)N;            // bucket: N*64 int2
    const size_t ENDu = BK + (size_t)N * 128;
    const size_t need_bytes = ENDu * 4;

    u32* ws = (u32*)d_ws;
    prep_kernel<<<62, 256, 0, stream>>>(mw1, mb1, mw2, mb2, uw1, ub1, uw2, ub2, ws);

    float* buf = (float*)d_out;
    const int nIterN = (N + 63) / 64;

    if (ws_size >= need_bytes) {
        // ---- gather path: no fp32 atomics ----
        u32*   Pb   = ws + PO;
        float* Qb   = (float*)(ws + QO);
        int*   deg  = (int*)(ws + DG);
        int2*  bkt  = (int2*)(ws + BK);

        pq_gemm<<<196, 256, 0, stream>>>(x, ws, Pb, 0, 0, 1, N, nIterN);
        pq_gemm<<<196, 256, 0, stream>>>(x, ws, Qb, 8, 1, 0, N, nIterN);

        hipMemsetAsync(deg, 0, (size_t)N * sizeof(int), stream);
        bucket_fill<<<(E + 255) / 256, 256, 0, stream>>>(pos, ei, deg, bkt, E);

        aggregate_kernel<<<1024, 256, 0, stream>>>(Pb, Qb, mw1 + 256 * H, ws + 53248,
                                                   deg, bkt, buf, N);
        node_mfma<<<256, 256, 0, stream>>>(x, buf, ws, N, nIterN);
    } else {
        // ---- fallback: round-3 atomic scatter path ----
        hipMemsetAsync(buf, 0, (size_t)N * H * sizeof(float), stream);
        edge_mfma<<<512, 256, 0, stream>>>(x, pos, ei, ws, buf, E, E / 64);
        node_mfma<<<256, 256, 0, stream>>>(x, buf, ws, N, nIterN);
    }
}

// Round 9
// 441.976 us; speedup vs baseline: 2.7926x; 1.9353x over previous
//
#include <hip/hip_runtime.h>
#include <math.h>

#define H 128

typedef unsigned short u16;
typedef unsigned int u32;
typedef __attribute__((ext_vector_type(4))) u32 u32x4;
typedef __attribute__((ext_vector_type(8))) __bf16 bf16x8;
typedef __attribute__((ext_vector_type(4))) float f32x4;
typedef __attribute__((ext_vector_type(16))) float f32x16;

union Frag { u32x4 u; bf16x8 b; };

__device__ __forceinline__ u16 bfr(float f) {            // f32 -> bf16 RNE
    union { float f; u32 i; } v; v.f = f;
    u32 r = v.i + 0x7fffu + ((v.i >> 16) & 1u);
    return (u16)(r >> 16);
}
__device__ __forceinline__ u32 pack2(float lo, float hi) {
    return (u32)bfr(lo) | ((u32)bfr(hi) << 16);
}
__device__ __forceinline__ float bflo(u32 w) {           // low bf16 -> f32
    union { u32 i; float f; } v; v.i = w << 16; return v.f;
}
__device__ __forceinline__ float bfhi(u32 w) {           // high bf16 -> f32
    union { u32 i; float f; } v; v.i = w & 0xffff0000u; return v.f;
}
__device__ __forceinline__ float silu(float v) {
    float e = __expf(-v);
    return v * __builtin_amdgcn_rcpf(1.0f + e);
}
__device__ __forceinline__ bf16x8 f8frag(float4 lo, float4 hi) {
    Frag f;
    f.u = (u32x4){pack2(lo.x, lo.y), pack2(lo.z, lo.w),
                  pack2(hi.x, hi.y), pack2(hi.z, hi.w)};
    return f.b;
}
__device__ __forceinline__ f32x16 mfma(bf16x8 a, bf16x8 b, f32x16 c) {
    return __builtin_amdgcn_mfma_f32_32x32x16_bf16(a, b, c, 0, 0, 0);
}
__device__ __forceinline__ f32x4 mfma16(bf16x8 a, bf16x8 b, f32x4 c) {
    return __builtin_amdgcn_mfma_f32_16x16x32_bf16(a, b, c, 0, 0, 0);
}
// VALU-pipe cross-lane add within 16-lane rows: v += row_ror(v, N)
#define DPP_RADD(v, ctrl) \
    (v) += __int_as_float(__builtin_amdgcn_update_dpp(0, __float_as_int(v), (ctrl), 0xf, 0xf, 1))

// ---------------------------------------------------------------------------
// ws frag region (u32 units):
//   mw1s @ 0      : 4ct x 17kb x 64lane x 4   (msg w1^T 32x32 frags; kb16 = dist+b1)
//   mw2s @ 17408  : 4ct x  9kb x 64lane x 4   (msg w2^T 32x32 frags; kb8 = b2)
//   uw1s @ 26624  : 4ct x 17kb x 64lane x 4   (upd w1^T 32x32 frags; kb16 = b1)
//   uw2s @ 44032  : 4ct x  9kb x 64lane x 4   (upd w2^T 32x32 frags; kb8 = b2)
//   m16s @ 53248  : 5kb x 8mt x 64lane x 4    (msg w2 16x16 A-frags; kb4 unused now)
//   wdp  @ 63488  : 64 u32                    (dist-row weights packed bf16)
// 32x32 A-frag (ct,kb,lane): W[k=kb*16+(lane>>5)*8+j][ct*32+(lane&31)]
// 16x16 A-frag (kb,mt,lane): W[k=kb*32+(lane>>4)*8+j][mt*16+(lane&15)]
// ---------------------------------------------------------------------------
__global__ void prep_kernel(const float* __restrict__ mw1, const float* __restrict__ mb1,
                            const float* __restrict__ mw2, const float* __restrict__ mb2,
                            const float* __restrict__ uw1, const float* __restrict__ ub1,
                            const float* __restrict__ uw2, const float* __restrict__ ub2,
                            u32* __restrict__ ws) {
    int t = blockIdx.x * blockDim.x + threadIdx.x;
    if (t >= 15936) return;
    if (t >= 15872) {
        // ---- dist-row weights, packed bf16 ----
        int i = t - 15872;                    // [0, 64)
        ws[63488 + i] = pack2(mw1[256 * H + 2 * i], mw1[256 * H + 2 * i + 1]);
        return;
    }
    if (t >= 13312) {
        // ---- 16x16 A-frags of msg w2 ----
        int slot = t - 13312;                 // (kb*8 + mt)*64 + lane
        int lane = slot & 63, fb = slot >> 6;
        int kb = fb >> 3, mt = fb & 7;
        int m = mt * 16 + (lane & 15);
        int quad = lane >> 4;
        u32 out[4];
        #pragma unroll
        for (int p = 0; p < 4; ++p) {
            float v[2];
            #pragma unroll
            for (int h = 0; h < 2; ++h) {
                int k = kb * 32 + quad * 8 + p * 2 + h;
                float val = 0.0f;
                if (k < 128)       val = mw2[(size_t)k * H + m];
                else if (k == 128) val = mb2[m];
                v[h] = val;
            }
            out[p] = pack2(v[0], v[1]);
        }
        u32* dst = ws + 53248 + (size_t)slot * 4;
        dst[0] = out[0]; dst[1] = out[1]; dst[2] = out[2]; dst[3] = out[3];
        return;
    }
    const float *W, *s0, *s1;
    int nK, slot, base;
    if (t < 4352)       { W = mw1; s0 = mw1 + 256 * H; s1 = mb1; nK = 256; slot = t;         base = 0;     }
    else if (t < 6656)  { W = mw2; s0 = mb2; s1 = nullptr;       nK = 128; slot = t - 4352;  base = 17408; }
    else if (t < 11008) { W = uw1; s0 = ub1; s1 = nullptr;       nK = 256; slot = t - 6656;  base = 26624; }
    else                { W = uw2; s0 = ub2; s1 = nullptr;       nK = 128; slot = t - 11008; base = 44032; }
    int lane = slot & 63, fb = slot >> 6;
    int ct, kb;
    if (nK == 256) { ct = fb / 17; kb = fb % 17; }
    else           { ct = fb / 9;  kb = fb % 9;  }
    int m = ct * 32 + (lane & 31);
    int q = lane >> 5;
    u32 out[4];
    #pragma unroll
    for (int p = 0; p < 4; ++p) {
        float v[2];
        #pragma unroll
        for (int h = 0; h < 2; ++h) {
            int k = kb * 16 + q * 8 + p * 2 + h;
            float val = 0.0f;
            if (k < nK)            val = W[(size_t)k * H + m];
            else if (k == nK)      val = s0 ? s0[m] : 0.0f;
            else if (k == nK + 1)  val = s1 ? s1[m] : 0.0f;
            v[h] = val;
        }
        out[p] = pack2(v[0], v[1]);
    }
    u32* dst = ws + base + (size_t)slot * 4;
    dst[0] = out[0]; dst[1] = out[1]; dst[2] = out[2]; dst[3] = out[3];
}

// ---------------------------------------------------------------------------
// pq_gemm: out[n] = x[n] @ W1[kbBase*16 : +128] (+ bias row if withBias).
// packP: store rows as packed bf16 (64 u32/row); else fp32 (128 f32/row).
// ---------------------------------------------------------------------------
__global__ __launch_bounds__(256, 2) void pq_gemm(
    const float* __restrict__ x, const u32* __restrict__ mw1s,
    void* __restrict__ outp, int kbBase, int withBias, int packP, int N, int nIter)
{
    const int lane = threadIdx.x & 63;
    const int q = lane >> 5, el = lane & 31;
    const int gw  = blockIdx.x * 4 + (threadIdx.x >> 6);
    const int gws = gridDim.x * 4;

    for (int it = gw; it < nIter; it += gws) {
        const int n0 = it * 64;
        const int nA = n0 + el, nB = n0 + 32 + el;
        const int ncA = (nA < N) ? nA : (N - 1);
        const int ncB = (nB < N) ? nB : (N - 1);
        const float* xA = x + (size_t)ncA * H;
        const float* xB = x + (size_t)ncB * H;

        f32x16 acc[2][4];
        #pragma unroll
        for (int s = 0; s < 2; ++s)
            #pragma unroll
            for (int ct = 0; ct < 4; ++ct) acc[s][ct] = (f32x16)0.0f;

        #pragma unroll
        for (int kb = 0; kb < 8; ++kb) {
            const int f = kb * 16 + q * 8;
            bf16x8 bA = f8frag(*(const float4*)(xA + f), *(const float4*)(xA + f + 4));
            bf16x8 bB = f8frag(*(const float4*)(xB + f), *(const float4*)(xB + f + 4));
            #pragma unroll
            for (int ct = 0; ct < 4; ++ct) {
                Frag a; a.u = *(const u32x4*)&mw1s[((size_t)(ct * 17 + kbBase + kb) * 64 + lane) * 4];
                acc[0][ct] = mfma(a.b, bA, acc[0][ct]);
                acc[1][ct] = mfma(a.b, bB, acc[1][ct]);
            }
        }
        if (withBias) {   // pad kb16: k=256 -> 0 (skip dist row), k=257 -> 1.0 (b1)
            Frag bp; bp.u = (u32x4){0, 0, 0, 0};
            if (q == 0) bp.u.x = pack2(0.0f, 1.0f);
            #pragma unroll
            for (int ct = 0; ct < 4; ++ct) {
                Frag a; a.u = *(const u32x4*)&mw1s[((size_t)(ct * 17 + 16) * 64 + lane) * 4];
                acc[0][ct] = mfma(a.b, bp.b, acc[0][ct]);
                acc[1][ct] = mfma(a.b, bp.b, acc[1][ct]);
            }
        }
        #pragma unroll
        for (int s = 0; s < 2; ++s) {
            const int nn = s ? nB : nA;
            if (nn < N) {
                if (packP) {
                    u32* prow = (u32*)outp + (size_t)nn * 64;
                    #pragma unroll
                    for (int ct = 0; ct < 4; ++ct)
                        #pragma unroll
                        for (int g = 0; g < 4; ++g) {
                            u32 a = pack2(acc[s][ct][4*g + 0], acc[s][ct][4*g + 1]);
                            u32 b = pack2(acc[s][ct][4*g + 2], acc[s][ct][4*g + 3]);
                            *(uint2*)(prow + ct * 16 + 4 * g + 2 * q) = make_uint2(a, b);
                        }
                } else {
                    float* orow = (float*)outp + (size_t)nn * H;
                    #pragma unroll
                    for (int ct = 0; ct < 4; ++ct)
                        #pragma unroll
                        for (int g = 0; g < 4; ++g) {
                            float4 v = { acc[s][ct][4*g + 0], acc[s][ct][4*g + 1],
                                         acc[s][ct][4*g + 2], acc[s][ct][4*g + 3] };
                            *(float4*)(orow + ct * 32 + 8 * g + 4 * q) = v;
                        }
                }
            }
        }
    }
}

// ---------------------------------------------------------------------------
// bucket_fill: per edge, slot = atomicAdd(deg[rec]); bucket[rec*64+slot] = (send, dist)
// ---------------------------------------------------------------------------
__global__ void bucket_fill(const float* __restrict__ pos, const int* __restrict__ ei,
                            int* __restrict__ deg, int2* __restrict__ bucket, int E)
{
    int e = blockIdx.x * blockDim.x + threadIdx.x;
    if (e >= E) return;
    const int s = ei[e];
    const int r = ei[E + e];
    const float dx = pos[s*3]   - pos[r*3];
    const float dy = pos[s*3+1] - pos[r*3+1];
    const float dz = pos[s*3+2] - pos[r*3+2];
    const float dist = sqrtf(dx*dx + dy*dy + dz*dz);
    int slot = atomicAdd(&deg[r], 1);
    if (slot < 64) bucket[(size_t)r * 64 + slot] = make_int2(s, __float_as_int(dist));
}

// ---------------------------------------------------------------------------
// aggregate (16x16, low-arch-pressure): one wave per node n. 16-edge tiles.
//   h_e = silu(P[send_e] + Q[n] + dist_e * wd)   (all three packed bf16)
//   D = w2^T A-frags (LDS) @ h B-frag + b2       (b2 via MFMA C-init from LDS)
//   sum += valid ? silu(D) : 0                   (col = own edge per lane)
//   reduce over 16 col-lanes via DPP row_ror     (pure VALU, zero LDS ops)
// Register-pressure notes (hard-won):
//   * arch/acc split: allocator uses ~half the __launch_bounds__ cap for arch
//     VGPRs when MFMA is present (R7: 84, R8: 128). Exceeding it => GB-scale
//     scratch spill (R5/R7/R8 measured 1.3-4.9 GB WRITE). Keep arch live-set
//     small: unroll 2 on kb, packed-bf16 Q/wd, no w2b/b2-pad MFMA.
//   * (256,2) only — (256,3)/(256,4) measured catastrophic spill.
// ---------------------------------------------------------------------------
__global__ __launch_bounds__(256, 2) void aggregate_kernel(
    const u32* __restrict__ Pbf, const u32* __restrict__ Qbf,
    const u32* __restrict__ wdp, const u32* __restrict__ ws16,
    const float* __restrict__ mb2,
    const int* __restrict__ deg, const int2* __restrict__ bucket,
    float* __restrict__ out, int N)
{
    __shared__ u32x4 af[2048];                        // 32 KiB: w2 16x16 A-frags kb<4
    __shared__ float b2s[128];                        // b2 fp32 (C-init source)
    for (int i = threadIdx.x; i < 2048; i += 256) af[i] = ((const u32x4*)ws16)[i];
    for (int i = threadIdx.x; i < 128; i += 256) b2s[i] = mb2[i];
    __syncthreads();

    const int lane = threadIdx.x & 63;
    const int quad = lane >> 4, col = lane & 15;

    // dist-row weights: loop-invariant, 16 persistent regs (packed bf16)
    u32x4 wdv[4];
    #pragma unroll
    for (int kb = 0; kb < 4; ++kb) wdv[kb] = ((const u32x4*)wdp)[kb * 4 + quad];

    const int gw  = blockIdx.x * 4 + (threadIdx.x >> 6);
    const int gws = gridDim.x * 4;

    for (int n = gw; n < N; n += gws) {
        int dn = deg[n]; dn = (dn > 64) ? 64 : dn;
        const int nt = (dn + 15) >> 4;
        const u32x4* Qrow = (const u32x4*)(Qbf + (size_t)n * 64);

        f32x4 sum[8];
        #pragma unroll
        for (int mt = 0; mt < 8; ++mt) sum[mt] = (f32x4){0.f, 0.f, 0.f, 0.f};

        for (int t = 0; t < nt; ++t) {
            const int eIdx = t * 16 + col;
            const bool valid = eIdx < dn;
            const int eC = valid ? eIdx : (dn - 1);
            const int2 rec = bucket[(size_t)n * 64 + eC];
            const u32x4* Prow = (const u32x4*)(Pbf + (size_t)rec.x * 64);
            const float dist = __int_as_float(rec.y);

            f32x4 acc[8];                             // C-init = b2 (per-row)
            #pragma unroll
            for (int mt = 0; mt < 8; ++mt)
                acc[mt] = *(const f32x4*)&b2s[mt * 16 + quad * 4];

            #pragma unroll 2
            for (int kb = 0; kb < 4; ++kb) {
                const u32x4 pc = Prow[kb * 4 + quad];
                const u32x4 qc = Qrow[kb * 4 + quad];
                const u32x4 wc = wdv[kb];
                const float v0 = silu(bflo(pc.x) + bflo(qc.x) + dist * bflo(wc.x));
                const float v1 = silu(bfhi(pc.x) + bfhi(qc.x) + dist * bfhi(wc.x));
                const float v2 = silu(bflo(pc.y) + bflo(qc.y) + dist * bflo(wc.y));
                const float v3 = silu(bfhi(pc.y) + bfhi(qc.y) + dist * bfhi(wc.y));
                const float v4 = silu(bflo(pc.z) + bflo(qc.z) + dist * bflo(wc.z));
                const float v5 = silu(bfhi(pc.z) + bfhi(qc.z) + dist * bfhi(wc.z));
                const float v6 = silu(bflo(pc.w) + bflo(qc.w) + dist * bflo(wc.w));
                const float v7 = silu(bfhi(pc.w) + bfhi(qc.w) + dist * bfhi(wc.w));
                Frag bf;
                bf.u = (u32x4){pack2(v0, v1), pack2(v2, v3), pack2(v4, v5), pack2(v6, v7)};
                if (!valid) bf.u = (u32x4){0, 0, 0, 0};
                #pragma unroll
                for (int mt = 0; mt < 8; ++mt) {
                    Frag a; a.u = af[(kb * 8 + mt) * 64 + lane];
                    acc[mt] = mfma16(a.b, bf.b, acc[mt]);
                }
            }
            // lane's D values all belong to its own column (= its own edge):
            // invalid columns (D == b2) are masked here.
            #pragma unroll
            for (int mt = 0; mt < 8; ++mt) {
                sum[mt][0] += valid ? silu(acc[mt][0]) : 0.0f;
                sum[mt][1] += valid ? silu(acc[mt][1]) : 0.0f;
                sum[mt][2] += valid ? silu(acc[mt][2]) : 0.0f;
                sum[mt][3] += valid ? silu(acc[mt][3]) : 0.0f;
            }
        }

        // reduce over the 16 column-lanes: DPP row rotations, pure VALU
        #pragma unroll
        for (int mt = 0; mt < 8; ++mt)
            #pragma unroll
            for (int r = 0; r < 4; ++r) {
                float v = sum[mt][r];
                DPP_RADD(v, 0x128);   // row_ror:8
                DPP_RADD(v, 0x124);   // row_ror:4
                DPP_RADD(v, 0x122);   // row_ror:2
                DPP_RADD(v, 0x121);   // row_ror:1
                sum[mt][r] = v;
            }
        if (col == 0) {               // lanes 0,16,32,48: rows quad*4..+3 per mt
            float* orow = out + (size_t)n * H;
            #pragma unroll
            for (int mt = 0; mt < 8; ++mt) {
                float4 v = { sum[mt][0], sum[mt][1], sum[mt][2], sum[mt][3] };
                *(float4*)(orow + mt * 16 + quad * 4) = v;
            }
        }
    }
}

// ---------------------------------------------------------------------------
// FALLBACK (ws too small): round-3 edge kernel with fp32 atomics.
// ---------------------------------------------------------------------------
__global__ __launch_bounds__(256, 2) void edge_mfma(
    const float* __restrict__ x, const float* __restrict__ pos,
    const int* __restrict__ ei, const u32* __restrict__ ws,
    float* __restrict__ aggr, int E, int nIter)
{
    __shared__ u32 lds[16384];
    {
        const u32x4* src = (const u32x4*)ws;
        u32x4* dst = (u32x4*)lds;
        for (int i = threadIdx.x; i < 4096; i += 256) {
            int ln = i & 63, fb = i >> 6, ct = fb >> 4, kb = fb & 15;
            dst[i] = src[(ct * 17 + kb) * 64 + ln];
        }
    }
    __syncthreads();
    const u32* wsl1 = ws;
    const u32* wsl2 = ws + 17408;

    const int lane = threadIdx.x & 63;
    const int q = lane >> 5, el = lane & 31;
    const int gw  = blockIdx.x * 4 + (threadIdx.x >> 6);
    const int gws = gridDim.x * 4;

    for (int it = gw; it < nIter; it += gws) {
        const int e0 = it * 64;
        const int sA = ei[e0 + el],      rA = ei[E + e0 + el];
        const int sB = ei[e0 + 32 + el], rB = ei[E + e0 + 32 + el];
        float dA, dB;
        {
            float ax = pos[sA*3] - pos[rA*3], ay = pos[sA*3+1] - pos[rA*3+1], az = pos[sA*3+2] - pos[rA*3+2];
            dA = sqrtf(ax*ax + ay*ay + az*az);
            float bx = pos[sB*3] - pos[rB*3], by = pos[sB*3+1] - pos[rB*3+1], bz = pos[sB*3+2] - pos[rB*3+2];
            dB = sqrtf(bx*bx + by*by + bz*bz);
        }
        const float* xsA = x + (size_t)sA * H; const float* xrA = x + (size_t)rA * H;
        const float* xsB = x + (size_t)sB * H; const float* xrB = x + (size_t)rB * H;

        f32x16 acc[2][4];
        #pragma unroll
        for (int s = 0; s < 2; ++s)
            #pragma unroll
            for (int ct = 0; ct < 4; ++ct) acc[s][ct] = (f32x16)0.0f;

        #pragma unroll
        for (int kb = 0; kb < 16; ++kb) {
            const int f = kb * 16 + q * 8;
            const float* pA = (f < H) ? (xsA + f) : (xrA + f - H);
            const float* pB = (f < H) ? (xsB + f) : (xrB + f - H);
            bf16x8 bA = f8frag(*(const float4*)pA, *(const float4*)(pA + 4));
            bf16x8 bB = f8frag(*(const float4*)pB, *(const float4*)(pB + 4));
            #pragma unroll
            for (int ct = 0; ct < 4; ++ct) {
                Frag a; a.u = *(const u32x4*)&lds[((ct * 16 + kb) * 64 + lane) * 4];
                acc[0][ct] = mfma(a.b, bA, acc[0][ct]);
                acc[1][ct] = mfma(a.b, bB, acc[1][ct]);
            }
        }
        {
            Frag bA, bB;
            bA.u = (u32x4){0,0,0,0}; bB.u = (u32x4){0,0,0,0};
            if (q == 0) { bA.u.x = pack2(dA, 1.0f); bB.u.x = pack2(dB, 1.0f); }
            #pragma unroll
            for (int ct = 0; ct < 4; ++ct) {
                Frag a; a.u = *(const u32x4*)&wsl1[((size_t)(ct * 17 + 16) * 64 + lane) * 4];
                acc[0][ct] = mfma(a.b, bA.b, acc[0][ct]);
                acc[1][ct] = mfma(a.b, bB.b, acc[1][ct]);
            }
        }

        #pragma unroll
        for (int s = 0; s < 2; ++s) {
            const int ridx = s ? rB : rA;
            u32 hp[4][4][2];
            #pragma unroll
            for (int ct = 0; ct < 4; ++ct)
                #pragma unroll
                for (int g = 0; g < 4; ++g) {
                    float v0 = silu(acc[s][ct][4*g + 0]);
                    float v1 = silu(acc[s][ct][4*g + 1]);
                    float v2 = silu(acc[s][ct][4*g + 2]);
                    float v3 = silu(acc[s][ct][4*g + 3]);
                    hp[ct][g][0] = pack2(v0, v1);
                    hp[ct][g][1] = pack2(v2, v3);
                }

            f32x16 acc2[4];
            #pragma unroll
            for (int ct = 0; ct < 4; ++ct) acc2[ct] = (f32x16)0.0f;

            #pragma unroll
            for (int kb2 = 0; kb2 < 8; ++kb2) {
                const int om = 2 * kb2 + q;
                const int op = 2 * kb2 + 1 - q;
                u32 sv0 = hp[op >> 2][op & 3][0];
                u32 sv1 = hp[op >> 2][op & 3][1];
                u32 r0 = (u32)__shfl((int)sv0, lane ^ 32);
                u32 r1 = (u32)__shfl((int)sv1, lane ^ 32);
                u32 w0 = hp[om >> 2][om & 3][0];
                u32 w1v = hp[om >> 2][om & 3][1];
                Frag bf;
                if (q == 0) bf.u = (u32x4){w0, w1v, r0, r1};
                else        bf.u = (u32x4){r0, r1, w0, w1v};
                #pragma unroll
                for (int ct2 = 0; ct2 < 4; ++ct2) {
                    Frag a; a.u = *(const u32x4*)&wsl2[((size_t)(ct2 * 9 + kb2) * 64 + lane) * 4];
                    acc2[ct2] = mfma(a.b, bf.b, acc2[ct2]);
                }
            }
            {
                Frag bf; bf.u = (u32x4){0,0,0,0};
                if (q == 0) bf.u.x = 0x00003F80u;
                #pragma unroll
                for (int ct2 = 0; ct2 < 4; ++ct2) {
                    Frag a; a.u = *(const u32x4*)&wsl2[((size_t)(ct2 * 9 + 8) * 64 + lane) * 4];
                    acc2[ct2] = mfma(a.b, bf.b, acc2[ct2]);
                }
            }
            float* arow = aggr + (size_t)ridx * H;
            #pragma unroll
            for (int ct2 = 0; ct2 < 4; ++ct2)
                #pragma unroll
                for (int r = 0; r < 16; ++r) {
                    int m = ct2 * 32 + (r & 3) + 8 * (r >> 2) + 4 * q;
                    atomicAdd(arow + m, silu(acc2[ct2][r]));
                }
        }
    }
}

// ---------------------------------------------------------------------------
// Node update MLP: update = silu([x, aggr] @ uw1 + ub1) @ uw2 + ub2
// buf == d_out: aggr rows on entry, overwritten with the final update.
// ---------------------------------------------------------------------------
__global__ __launch_bounds__(256, 2) void node_mfma(
    const float* __restrict__ x, float* __restrict__ buf,
    const u32* __restrict__ ws, int N, int nIter)
{
    __shared__ u32 lds[16384];
    const u32* wsl1 = ws + 26624;
    const u32* wsl2 = ws + 44032;
    {
        const u32x4* src = (const u32x4*)wsl1;
        u32x4* dst = (u32x4*)lds;
        for (int i = threadIdx.x; i < 4096; i += 256) {
            int ln = i & 63, fb = i >> 6, ct = fb >> 4, kb = fb & 15;
            dst[i] = src[(ct * 17 + kb) * 64 + ln];
        }
    }
    __syncthreads();

    const int lane = threadIdx.x & 63;
    const int q = lane >> 5, el = lane & 31;
    const int gw  = blockIdx.x * 4 + (threadIdx.x >> 6);
    const int gws = gridDim.x * 4;

    for (int it = gw; it < nIter; it += gws) {
        const int n0 = it * 64;
        const int nA = n0 + el, nB = n0 + 32 + el;
        const int ncA = (nA < N) ? nA : (N - 1);
        const int ncB = (nB < N) ? nB : (N - 1);
        const float* xA = x + (size_t)ncA * H;  const float* gA = buf + (size_t)ncA * H;
        const float* xB = x + (size_t)ncB * H;  const float* gB = buf + (size_t)ncB * H;

        f32x16 acc[2][4];
        #pragma unroll
        for (int s = 0; s < 2; ++s)
            #pragma unroll
            for (int ct = 0; ct < 4; ++ct) acc[s][ct] = (f32x16)0.0f;

        #pragma unroll
        for (int kb = 0; kb < 16; ++kb) {
            const int f = kb * 16 + q * 8;
            const float* pA = (f < H) ? (xA + f) : (gA + f - H);
            const float* pB = (f < H) ? (xB + f) : (gB + f - H);
            bf16x8 bA = f8frag(*(const float4*)pA, *(const float4*)(pA + 4));
            bf16x8 bB = f8frag(*(const float4*)pB, *(const float4*)(pB + 4));
            #pragma unroll
            for (int ct = 0; ct < 4; ++ct) {
                Frag a; a.u = *(const u32x4*)&lds[((ct * 16 + kb) * 64 + lane) * 4];
                acc[0][ct] = mfma(a.b, bA, acc[0][ct]);
                acc[1][ct] = mfma(a.b, bB, acc[1][ct]);
            }
        }
        {
            Frag bp; bp.u = (u32x4){0,0,0,0};
            if (q == 0) bp.u.x = 0x00003F80u;
            #pragma unroll
            for (int ct = 0; ct < 4; ++ct) {
                Frag a; a.u = *(const u32x4*)&wsl1[((size_t)(ct * 17 + 16) * 64 + lane) * 4];
                acc[0][ct] = mfma(a.b, bp.b, acc[0][ct]);
                acc[1][ct] = mfma(a.b, bp.b, acc[1][ct]);
            }
        }

        #pragma unroll
        for (int s = 0; s < 2; ++s) {
            const int nn = s ? nB : nA;
            u32 hp[4][4][2];
            #pragma unroll
            for (int ct = 0; ct < 4; ++ct)
                #pragma unroll
                for (int g = 0; g < 4; ++g) {
                    float v0 = silu(acc[s][ct][4*g + 0]);
                    float v1 = silu(acc[s][ct][4*g + 1]);
                    float v2 = silu(acc[s][ct][4*g + 2]);
                    float v3 = silu(acc[s][ct][4*g + 3]);
                    hp[ct][g][0] = pack2(v0, v1);
                    hp[ct][g][1] = pack2(v2, v3);
                }

            f32x16 acc2[4];
            #pragma unroll
            for (int ct = 0; ct < 4; ++ct) acc2[ct] = (f32x16)0.0f;

            #pragma unroll
            for (int kb2 = 0; kb2 < 8; ++kb2) {
                const int om = 2 * kb2 + q;
                const int op = 2 * kb2 + 1 - q;
                u32 sv0 = hp[op >> 2][op & 3][0];
                u32 sv1 = hp[op >> 2][op & 3][1];
                u32 r0 = (u32)__shfl((int)sv0, lane ^ 32);
                u32 r1 = (u32)__shfl((int)sv1, lane ^ 32);
                u32 w0 = hp[om >> 2][om & 3][0];
                u32 w1v = hp[om >> 2][om & 3][1];
                Frag bf;
                if (q == 0) bf.u = (u32x4){w0, w1v, r0, r1};
                else        bf.u = (u32x4){r0, r1, w0, w1v};
                #pragma unroll
                for (int ct2 = 0; ct2 < 4; ++ct2) {
                    Frag a; a.u = *(const u32x4*)&wsl2[((size_t)(ct2 * 9 + kb2) * 64 + lane) * 4];
                    acc2[ct2] = mfma(a.b, bf.b, acc2[ct2]);
                }
            }
            {
                Frag bf; bf.u = (u32x4){0,0,0,0};
                if (q == 0) bf.u.x = 0x00003F80u;
                #pragma unroll
                for (int ct2 = 0; ct2 < 4; ++ct2) {
                    Frag a; a.u = *(const u32x4*)&wsl2[((size_t)(ct2 * 9 + 8) * 64 + lane) * 4];
                    acc2[ct2] = mfma(a.b, bf.b, acc2[ct2]);
                }
            }
            if (nn < N) {
                float* orow = buf + (size_t)nn * H;
                #pragma unroll
                for (int ct2 = 0; ct2 < 4; ++ct2)
                    #pragma unroll
                    for (int g = 0; g < 4; ++g) {
                        float4 v = { acc2[ct2][4*g + 0], acc2[ct2][4*g + 1],
                                     acc2[ct2][4*g + 2], acc2[ct2][4*g + 3] };
                        *(float4*)(orow + ct2 * 32 + 8 * g + 4 * q) = v;
                    }
            }
        }
    }
}

extern "C" void kernel_launch(void* const* d_in, const int* in_sizes, int n_in,
                              void* d_out, int out_size, void* d_ws, size_t ws_size,
                              hipStream_t stream) {
    const float* x    = (const float*)d_in[0];
    const float* pos  = (const float*)d_in[1];
    const int*   ei   = (const int*)d_in[2];
    const float* mw1  = (const float*)d_in[3];
    const float* mb1  = (const float*)d_in[4];
    const float* mw2  = (const float*)d_in[5];
    const float* mb2  = (const float*)d_in[6];
    const float* uw1  = (const float*)d_in[7];
    const float* ub1  = (const float*)d_in[8];
    const float* uw2  = (const float*)d_in[9];
    const float* ub2  = (const float*)d_in[10];

    const int N = in_sizes[0] / H;
    const int E = in_sizes[2] / 2;

    // ws layout (u32 units)
    const size_t FRAGS = 53248 + 10240 + 64;     // 32x32 frags + 16x16 frags + wdp
    const size_t PO = FRAGS;                     // P: N*64 u32 (packed bf16 rows)
    const size_t QO = PO + (size_t)N * 64;       // Q: N*64 u32 (packed bf16 rows)
    const size_t DG = QO + (size_t)N * 64;       // deg: N int
    const size_t BK = DG + (size_t)N;            // bucket: N*64 int2
    const size_t ENDu = BK + (size_t)N * 128;
    const size_t need_bytes = ENDu * 4;

    u32* ws = (u32*)d_ws;
    prep_kernel<<<63, 256, 0, stream>>>(mw1, mb1, mw2, mb2, uw1, ub1, uw2, ub2, ws);

    float* buf = (float*)d_out;
    const int nIterN = (N + 63) / 64;

    if (ws_size >= need_bytes) {
        // ---- gather path: no fp32 atomics ----
        u32*   Pb   = ws + PO;
        u32*   Qb   = ws + QO;
        int*   deg  = (int*)(ws + DG);
        int2*  bkt  = (int2*)(ws + BK);

        pq_gemm<<<196, 256, 0, stream>>>(x, ws, Pb, 0, 0, 1, N, nIterN);
        pq_gemm<<<196, 256, 0, stream>>>(x, ws, Qb, 8, 1, 1, N, nIterN);

        hipMemsetAsync(deg, 0, (size_t)N * sizeof(int), stream);
        bucket_fill<<<(E + 255) / 256, 256, 0, stream>>>(pos, ei, deg, bkt, E);

        aggregate_kernel<<<1024, 256, 0, stream>>>(Pb, Qb, ws + 63488, ws + 53248,
                                                   mb2, deg, bkt, buf, N);
        node_mfma<<<256, 256, 0, stream>>>(x, buf, ws, N, nIterN);
    } else {
        // ---- fallback: round-3 atomic scatter path ----
        hipMemsetAsync(buf, 0, (size_t)N * H * sizeof(float), stream);
        edge_mfma<<<512, 256, 0, stream>>>(x, pos, ei, ws, buf, E, E / 64);
        node_mfma<<<256, 256, 0, stream>>>(x, buf, ws, N, nIterN);
    }
}